// Round 15
// baseline (2425.421 us; speedup 1.0000x reference)
//
#include <hip/hip_runtime.h>
#include <math.h>

// Problem: B=8, C=256, N=H*W=1024, nh=8, dk=dv=32.
// Round 15: THE FIX — d_out is FLOAT32 (reference output dtype), not bf16.
// Eleven rounds of bit-identical absmax (0.60546875) are fully explained by
// writing u16 bf16 into an fp32 buffer: fp32[i] decodes as out[2i+1] with
// mantissa noise -> absmax = max|out[2i+1]-ref[i]| ~ 0.60 over 1M pairs
// (also why R6's u16[0] stamp and R14's half-buffer tracer were invisible).
// Inputs are fp32-stored (R1-3 NaN -> R4 finite flip), values bf16-rounded
// (hence the 2%*max|ref| threshold). This round: same audited scalar
// pipeline, fp32 reads (with probe), bf16 ws, FLOAT32 output writes.
typedef unsigned short u16;

__device__ __forceinline__ float bf_f(u16 u) {
  union { unsigned u; float f; } c; c.u = ((unsigned)u) << 16; return c.f;
}
__device__ __forceinline__ u16 f_bf(float f) {
  union { float f; unsigned u; } c; c.f = f;
  unsigned u = c.u;
  u += 0x7fffu + ((u >> 16) & 1u);   // round-to-nearest-even
  return (u16)(u >> 16);
}
// Block-uniform dtype probe (first 64 u16s). fp32-stored data (incl.
// bf16-rounded values, whose low halves are 0x0000) shows "wild" exponent
// fields in the low u16s; true bf16 storage keeps them in a narrow band.
__device__ __forceinline__ bool is_f32(const void* p) {
  const u16* u = (const u16*)p;
  int wild = 0;
  for (int i = 0; i < 64; ++i) {
    const int e = (u[i] >> 7) & 0xff;
    if (e >= 0xC0 || e <= 0x30) ++wild;
  }
  return wild >= 4;
}
__device__ __forceinline__ float gv(const void* p, size_t i, bool f32) {
  return f32 ? ((const float*)p)[i] : bf_f(((const u16*)p)[i]);
}

// ---------------------------------------------------------------------------
// K1: QKV projection. Grid (4 nt, 256 oc, 8 b), 256 thr; thread -> one n.
// ws layout [(b*256+oc)][n] == [bh][d][n], oc = h*32+d, bf16.
// q scaled by dk^-0.5 after bias (reference order).
// ---------------------------------------------------------------------------
__global__ void r15_qkv(const void* x, const void* Wq, const void* bq,
                        const void* Wk, const void* bk,
                        const void* Wv, const void* bv,
                        u16* q, u16* k, u16* v)
{
  const bool xf = is_f32(x), wf = is_f32(Wq);
  const int n = blockIdx.x * 256 + threadIdx.x;
  const int oc = blockIdx.y, b = blockIdx.z;
  float aq = 0.f, ak = 0.f, av = 0.f;
  for (int c = 0; c < 256; ++c) {
    const float xv = gv(x, ((size_t)b * 256 + c) * 1024 + n, xf);
    aq = fmaf(gv(Wq, (size_t)oc * 256 + c, wf), xv, aq);
    ak = fmaf(gv(Wk, (size_t)oc * 256 + c, wf), xv, ak);
    av = fmaf(gv(Wv, (size_t)oc * 256 + c, wf), xv, av);
  }
  const size_t o = ((size_t)b * 256 + oc) * 1024 + n;
  q[o] = f_bf((aq + gv(bq, oc, wf)) * 0.17677669529663687f);
  k[o] = f_bf(ak + gv(bk, oc, wf));
  v[o] = f_bf(av + gv(bv, oc, wf));
}

// ---------------------------------------------------------------------------
// K2: attention. Grid (1024 n, 64 bh), 256 thr; full softmax per block.
// Head output -> d_out (FLOAT32) at [b][h*32+d][n]; K3 rewrites in place.
// ---------------------------------------------------------------------------
__global__ void r15_attn(const u16* q, const u16* k, const u16* v, float* out)
{
  __shared__ float pl[1024];
  __shared__ float red[257];
  __shared__ float qs[32];
  const int t = threadIdx.x;
  const int n = blockIdx.x, bh = blockIdx.y;
  const size_t base = (size_t)bh * 32 * 1024;

  if (t < 32) qs[t] = bf_f(q[base + (size_t)t * 1024 + n]);
  __syncthreads();

  float sv[4], lmax = -1e30f;   // no Inf in datapath (fast-math-safe)
  for (int j = 0; j < 4; ++j) {
    const int m = t * 4 + j;
    float s = 0.f;
    for (int d = 0; d < 32; ++d)
      s = fmaf(qs[d], bf_f(k[base + (size_t)d * 1024 + m]), s);
    sv[j] = s;
    lmax = fmaxf(lmax, s);
  }
  red[t] = lmax;
  __syncthreads();
  if (t == 0) {
    float mm = red[0];
    for (int i = 1; i < 256; ++i) mm = fmaxf(mm, red[i]);
    red[256] = mm;
  }
  __syncthreads();
  const float mx = red[256];
  float ls = 0.f;
  for (int j = 0; j < 4; ++j) {
    const float p = __expf(sv[j] - mx);
    pl[t * 4 + j] = p;
    ls += p;
  }
  __syncthreads();
  red[t] = ls;
  __syncthreads();
  if (t == 0) {
    float ss = 0.f;
    for (int i = 0; i < 256; ++i) ss += red[i];
    red[256] = ss;
  }
  __syncthreads();
  const float invl = 1.0f / red[256];
  __syncthreads();

  // o[d] = sum_m pl[m]*v[d][m]; thread (d = t>>3, sub = t&7) covers 128 m
  const int d = t >> 3, sub = t & 7;
  float part = 0.f;
  for (int i = 0; i < 128; ++i) {
    const int m = sub * 128 + i;
    part = fmaf(pl[m], bf_f(v[base + (size_t)d * 1024 + m]), part);
  }
  red[t] = part;
  __syncthreads();
  if (t < 32) {
    float o = 0.f;
    for (int s8 = 0; s8 < 8; ++s8) o += red[t * 8 + s8];
    out[base + (size_t)t * 1024 + n] = o * invl;   // FLOAT32 write
  }
}

// ---------------------------------------------------------------------------
// K3: in-place out-projection on fp32 d_out. Grid (32 nt, 8 b), 256 thr.
// Block stages its 32-n slab (all 256 channels, fp32) into LDS, barriers,
// overwrites only that slab. Slabs disjoint across blocks. LDS 33.3KB.
// ---------------------------------------------------------------------------
__global__ void r15_oproj(const void* Wo, const void* bo, float* out)
{
  __shared__ float o2t[32][260];   // [n_local][c], padded stride
  const bool wf = is_f32(Wo);
  const int t = threadIdx.x;
  const int nt = blockIdx.x, b = blockIdx.y;

  {  // stage: thread t = channel c, 32 contiguous n
    const float* src = out + ((size_t)b * 256 + t) * 1024 + nt * 32;
    for (int i = 0; i < 32; ++i) o2t[i][t] = src[i];
  }
  __syncthreads();

  const int nn = t & 31, qg = t >> 5;   // qg in [0,8): 32 oc each
  for (int oi = 0; oi < 32; ++oi) {
    const int oc = qg * 32 + oi;
    float a = 0.f;
    for (int c = 0; c < 256; ++c)
      a = fmaf(gv(Wo, (size_t)oc * 256 + c, wf), o2t[nn][c], a);
    out[((size_t)b * 256 + oc) * 1024 + nt * 32 + nn] =
        a + gv(bo, oc, wf);   // FLOAT32 write
  }
}

// ---------------------------------------------------------------------------
extern "C" void kernel_launch(void* const* d_in, const int* in_sizes, int n_in,
                              void* d_out, int out_size, void* d_ws, size_t ws_size,
                              hipStream_t stream) {
  (void)in_sizes; (void)n_in; (void)out_size; (void)ws_size;
  char* ws = (char*)d_ws;                    // 12 MB of workspace (bf16 q/k/v)
  u16* q = (u16*)(ws);                       // [bh][d][n] bf16, 4MB
  u16* k = (u16*)(ws + (4u << 20));          // 4MB
  u16* v = (u16*)(ws + (8u << 20));          // 4MB
  float* out = (float*)d_out;                // FLOAT32 output buffer

  r15_qkv<<<dim3(4, 256, 8), 256, 0, stream>>>(
      d_in[0], d_in[1], d_in[2], d_in[3], d_in[4], d_in[5], d_in[6], q, k, v);
  r15_attn<<<dim3(1024, 64), 256, 0, stream>>>(q, k, v, out);
  r15_oproj<<<dim3(32, 8), 256, 0, stream>>>(d_in[7], d_in[8], out);
}

// Round 16
// 287.017 us; speedup vs baseline: 8.4504x; 8.4504x over previous
//
#include <hip/hip_runtime.h>
#include <math.h>

// Problem: B=8, C=256, N=H*W=1024, nh=8, dk=dv=32.
// Confirmed (R15 PASS): inputs fp32, output fp32, ws >= 12MB functional.
// Round 16: MFMA pipeline.
//   K1 qkv  : VALU GEMM, fp32 in -> bf16 ws. q,k:[bh][n][d], v:[bh][d][n].
//   K2 attn : flash attention, mfma_f32_16x16x32_bf16, fp32 out -> d_out.
//   K3 oproj: in-place on d_out, block owns (b, 32-n slab) for all 256 oc.
typedef unsigned short u16;
typedef __attribute__((ext_vector_type(4))) unsigned short u16x4;
typedef __attribute__((ext_vector_type(8))) unsigned short u16x8;
typedef __attribute__((ext_vector_type(8))) short s16x8;   // MFMA A/B frag
typedef __attribute__((ext_vector_type(4))) float f32x4;   // MFMA C/D

__device__ __forceinline__ float bf2f(u16 u) {
  union { unsigned u; float f; } c; c.u = ((unsigned)u) << 16; return c.f;
}
__device__ __forceinline__ u16 f2bf(float f) {
  union { float f; unsigned u; } c; c.f = f;
  unsigned u = c.u;
  u += 0x7fffu + ((u >> 16) & 1u);   // round-to-nearest-even
  return (u16)(u >> 16);
}
__device__ __forceinline__ u16x8 ld16(const void* p) { u16x8 v; __builtin_memcpy(&v, p, 16); return v; }
__device__ __forceinline__ void st16(void* p, u16x8 v) { __builtin_memcpy(p, &v, 16); }
__device__ __forceinline__ u16x4 ld8(const void* p)  { u16x4 v; __builtin_memcpy(&v, p, 8);  return v; }
__device__ __forceinline__ void st8(void* p, u16x4 v)  { __builtin_memcpy(p, &v, 8); }
__device__ __forceinline__ f32x4 ldf4(const void* p) { f32x4 v; __builtin_memcpy(&v, p, 16); return v; }
__device__ __forceinline__ void stf4(void* p, f32x4 v) { __builtin_memcpy(p, &v, 16); }
__device__ __forceinline__ s16x8 frag16(const void* p) { s16x8 v; __builtin_memcpy(&v, p, 16); return v; }

// ---------------------------------------------------------------------------
// K1: QKV projection. Block 256 = (32 d, 8 nsub); tile 32 oc x 64 n; K=256
// in 4 chunks of 64. Grid (16 ntile, 8 h, 8 b).
// LDS: 3 x Wt[64][32] bf16 (12KB) + xt[256][64] bf16 xor-swizzled (32KB).
// ---------------------------------------------------------------------------
__global__ __launch_bounds__(256) void r16_qkv(
    const float* __restrict__ x,
    const float* __restrict__ Wq, const float* __restrict__ bq,
    const float* __restrict__ Wk, const float* __restrict__ bk,
    const float* __restrict__ Wv, const float* __restrict__ bv,
    u16* __restrict__ qo, u16* __restrict__ ko, u16* __restrict__ vo)
{
  __shared__ u16 wqt[64][32];    // wqt[c'][d] = Wq[h*32+d][cc0+c']
  __shared__ u16 wkt[64][32];
  __shared__ u16 wvt[64][32];
  __shared__ u16 xt[256][64];    // xt[c][(j ^ (c&7))*8 + jj]

  const int t = threadIdx.x;
  const int ntile = blockIdx.x, h = blockIdx.y, b = blockIdx.z;
  const int n0 = ntile * 64;
  const int d = t & 31, cg = t >> 5;

  {  // x tile: row c = t, 64 n (fp32 -> bf16), xor-swizzled 8-elem groups
    const float* xrow = x + ((size_t)b * 256 + t) * 1024 + n0;
#pragma unroll
    for (int j = 0; j < 8; ++j) {
      const f32x4 lo = ldf4(xrow + j * 8);
      const f32x4 hi = ldf4(xrow + j * 8 + 4);
      u16x8 v;
#pragma unroll
      for (int i = 0; i < 4; ++i) { v[i] = f2bf(lo[i]); v[4 + i] = f2bf(hi[i]); }
      st16(&xt[t][(j ^ (t & 7)) * 8], v);
    }
  }

  const int nsub = t >> 5;
  float accq[8], acck[8], accv[8];
#pragma unroll
  for (int j = 0; j < 8; ++j) { accq[j] = 0.f; acck[j] = 0.f; accv[j] = 0.f; }

  const float* wq_row = Wq + (h * 32 + d) * 256;
  const float* wk_row = Wk + (h * 32 + d) * 256;
  const float* wv_row = Wv + (h * 32 + d) * 256;

  for (int cc0 = 0; cc0 < 256; cc0 += 64) {
    __syncthreads();   // protect prev chunk tiles (and x-tile on iter 0)
#pragma unroll
    for (int i = 0; i < 2; ++i) {
      const int cl = cg * 8 + i * 4;
      const int c = cc0 + cl;
      const f32x4 a = ldf4(wq_row + c);
      wqt[cl+0][d] = f2bf(a.x); wqt[cl+1][d] = f2bf(a.y);
      wqt[cl+2][d] = f2bf(a.z); wqt[cl+3][d] = f2bf(a.w);
      const f32x4 e = ldf4(wk_row + c);
      wkt[cl+0][d] = f2bf(e.x); wkt[cl+1][d] = f2bf(e.y);
      wkt[cl+2][d] = f2bf(e.z); wkt[cl+3][d] = f2bf(e.w);
      const f32x4 g = ldf4(wv_row + c);
      wvt[cl+0][d] = f2bf(g.x); wvt[cl+1][d] = f2bf(g.y);
      wvt[cl+2][d] = f2bf(g.z); wvt[cl+3][d] = f2bf(g.w);
    }
    __syncthreads();

    for (int cl = 0; cl < 64; ++cl) {
      const int c = cc0 + cl;
      const float wqv = bf2f(wqt[cl][d]);
      const float wkv = bf2f(wkt[cl][d]);
      const float wvv = bf2f(wvt[cl][d]);
      const u16x8 xv = ld16(&xt[c][(nsub ^ (c & 7)) * 8]);  // b128 broadcast
#pragma unroll
      for (int j = 0; j < 8; ++j) {
        const float xf = bf2f(xv[j]);
        accq[j] = fmaf(wqv, xf, accq[j]);
        acck[j] = fmaf(wkv, xf, acck[j]);
        accv[j] = fmaf(wvv, xf, accv[j]);
      }
    }
  }

  const float bqv = bq[h * 32 + d];
  const float bkv = bk[h * 32 + d];
  const float bvv = bv[h * 32 + d];
  const size_t bh = (size_t)(b * 8 + h);
#pragma unroll
  for (int j = 0; j < 8; ++j) {
    const int n = n0 + nsub * 8 + j;
    // scale after bias, matching reference (q = (Wx+b) * dk^-0.5)
    qo[(bh * 1024 + n) * 32 + d] = f2bf((accq[j] + bqv) * 0.17677669529663687f);
    ko[(bh * 1024 + n) * 32 + d] = f2bf(acck[j] + bkv);
  }
  u16x8 v8;
#pragma unroll
  for (int j = 0; j < 8; ++j) v8[j] = f2bf(accv[j] + bvv);
  st16(vo + (bh * 32 + d) * 1024 + n0 + nsub * 8, v8);   // [bh][d][n]
}

// ---------------------------------------------------------------------------
// K2: flash attention, mfma_f32_16x16x32_bf16 (dk=32 = one K-step).
// Grid (16 qtiles, 64 bh); 4 waves x 16 queries. 32-key chunks in LDS.
// Layouts (m89/m74-verified): A[m=lane&15][k=quad*8+j];
// B[k=quad*8+j][n=lane&15]; C/D row=quad*4+reg, col=lane&15.
// Online softmax per C-row; P C-layout -> A-layout via barriered LDS.
// fp32 head output -> d_out[b][h*32+d][n].
// ---------------------------------------------------------------------------
__global__ __launch_bounds__(256) void r16_attn(
    const u16* __restrict__ qw, const u16* __restrict__ kw,
    const u16* __restrict__ vw, float* __restrict__ out)
{
  __shared__ u16 klds[32][32];      // [key][dk]
  __shared__ u16 vlds[32][32];      // [d][key]  (vw is [bh][d][n])
  __shared__ u16 plds[4][16][40];   // per-wave P, padded stride 40
  __shared__ float otf[32][72];     // [d][q_local] fp32, padded stride 72

  const int t = threadIdx.x;
  const int qtile = blockIdx.x;
  const int bh = blockIdx.y;
  const int w = t >> 6, lane = t & 63, l15 = lane & 15, quad = lane >> 4;

  const s16x8 qfrag = frag16(
      qw + ((size_t)bh * 1024 + qtile * 64 + w * 16 + l15) * 32 + quad * 8);

  f32x4 o0 = {0.f, 0.f, 0.f, 0.f}, o1 = {0.f, 0.f, 0.f, 0.f};
  float mrun[4], lrun[4];
#pragma unroll
  for (int r = 0; r < 4; ++r) { mrun[r] = -1e30f; lrun[r] = 0.f; }

  const int srow = t >> 3, scol = (t & 7) * 4;   // staging: 8B/thread

  for (int kb = 0; kb < 32; ++kb) {
    st8(&klds[srow][scol],
        ld8(kw + ((size_t)bh * 1024 + kb * 32 + srow) * 32 + scol));
    st8(&vlds[srow][scol],
        ld8(vw + ((size_t)bh * 32 + srow) * 1024 + kb * 32 + scol));
    __syncthreads();

    const s16x8 kf0 = frag16(&klds[l15][quad * 8]);
    const s16x8 kf1 = frag16(&klds[16 + l15][quad * 8]);
    const f32x4 zz = {0.f, 0.f, 0.f, 0.f};
    f32x4 s0 = __builtin_amdgcn_mfma_f32_16x16x32_bf16(qfrag, kf0, zz, 0, 0, 0);
    f32x4 s1 = __builtin_amdgcn_mfma_f32_16x16x32_bf16(qfrag, kf1, zz, 0, 0, 0);

    float alpha[4], p0[4], p1[4];
#pragma unroll
    for (int r = 0; r < 4; ++r) {
      float mx = fmaxf(s0[r], s1[r]);
      mx = fmaxf(mx, __shfl_xor(mx, 1));
      mx = fmaxf(mx, __shfl_xor(mx, 2));
      mx = fmaxf(mx, __shfl_xor(mx, 4));
      mx = fmaxf(mx, __shfl_xor(mx, 8));
      const float mnew = fmaxf(mrun[r], mx);
      alpha[r] = __expf(mrun[r] - mnew);
      p0[r] = __expf(s0[r] - mnew);
      p1[r] = __expf(s1[r] - mnew);
      float rs = p0[r] + p1[r];
      rs += __shfl_xor(rs, 1);
      rs += __shfl_xor(rs, 2);
      rs += __shfl_xor(rs, 4);
      rs += __shfl_xor(rs, 8);
      lrun[r] = lrun[r] * alpha[r] + rs;
      mrun[r] = mnew;
    }
#pragma unroll
    for (int r = 0; r < 4; ++r) {
      o0[r] *= alpha[r];
      o1[r] *= alpha[r];
      plds[w][quad * 4 + r][l15]      = f2bf(p0[r]);   // C-layout [q][key]
      plds[w][quad * 4 + r][16 + l15] = f2bf(p1[r]);
    }
    __syncthreads();   // fence plds write -> read
    const s16x8 pfrag = frag16(&plds[w][l15][quad * 8]);
    const s16x8 vf0 = frag16(&vlds[l15][quad * 8]);
    const s16x8 vf1 = frag16(&vlds[16 + l15][quad * 8]);
    o0 = __builtin_amdgcn_mfma_f32_16x16x32_bf16(pfrag, vf0, o0, 0, 0, 0);
    o1 = __builtin_amdgcn_mfma_f32_16x16x32_bf16(pfrag, vf1, o1, 0, 0, 0);
    __syncthreads();   // protect klds/vlds/plds before next chunk
  }

  // epilogue: normalize, transpose via LDS, fp32 store to d_out
#pragma unroll
  for (int r = 0; r < 4; ++r) {
    const float inv = 1.0f / lrun[r];
    otf[l15][w * 16 + quad * 4 + r]      = o0[r] * inv;
    otf[16 + l15][w * 16 + quad * 4 + r] = o1[r] * inv;
  }
  __syncthreads();
  {
    const int dd = t >> 3, i = t & 7;
    const int b = bh >> 3, hh = bh & 7;
    float* dst = out + ((size_t)b * 256 + hh * 32 + dd) * 1024 + qtile * 64 + i * 8;
    f32x4 v0, v1;
#pragma unroll
    for (int jj = 0; jj < 4; ++jj) { v0[jj] = otf[dd][i * 8 + jj];
                                     v1[jj] = otf[dd][i * 8 + 4 + jj]; }
    stf4(dst, v0); stf4(dst + 4, v1);
  }
}

// ---------------------------------------------------------------------------
// K3: in-place out-projection on fp32 d_out. Grid (32 nt, 8 b); block owns
// the (b, 32-n) slab for ALL 256 oc (read slab -> barrier -> overwrite).
// LDS: xts[256][34] bf16 (17KB) + wot[256][32] bf16 (16KB).
// Thread (d = t&31, ng = t>>5): 4 n values, looping 8 octiles of 32 oc.
// ---------------------------------------------------------------------------
__global__ __launch_bounds__(256) void r16_oproj(
    const float* __restrict__ Wo, const float* __restrict__ bo,
    float* __restrict__ out)
{
  __shared__ u16 xts[256][34];   // [c][n_local], padded stride 34
  __shared__ u16 wot[256][32];   // [c][d] for current octile
  const int t = threadIdx.x;
  const int nt = blockIdx.x, b = blockIdx.y;

  {  // stage slab: thread t = channel c, 32 contiguous n (fp32 -> bf16)
    const float* src = out + ((size_t)b * 256 + t) * 1024 + nt * 32;
#pragma unroll
    for (int i = 0; i < 32; ++i) xts[t][i] = f2bf(src[i]);
  }

  const int d = t & 31, cg = t >> 5, ng = t >> 5;

  for (int oct = 0; oct < 8; ++oct) {
    __syncthreads();   // slab staged (oct=0) / prev wot reads done
    {  // stage Wo chunk for oc = oct*32 + d
      const float* wrow = Wo + (oct * 32 + d) * 256;
#pragma unroll
      for (int i = 0; i < 8; ++i) {
        const int c = cg * 32 + i * 4;
        const f32x4 a = ldf4(wrow + c);
        wot[c+0][d] = f2bf(a.x); wot[c+1][d] = f2bf(a.y);
        wot[c+2][d] = f2bf(a.z); wot[c+3][d] = f2bf(a.w);
      }
    }
    __syncthreads();

    float acc[4] = {0.f, 0.f, 0.f, 0.f};
    for (int c = 0; c < 256; ++c) {
      const float wv = bf2f(wot[c][d]);
#pragma unroll
      for (int j = 0; j < 4; ++j)
        acc[j] = fmaf(wv, bf2f(xts[c][ng * 4 + j]), acc[j]);
    }
    const int oc = oct * 32 + d;
    const float bov = bo[oc];
    f32x4 r;
#pragma unroll
    for (int j = 0; j < 4; ++j) r[j] = acc[j] + bov;
    stf4(out + ((size_t)b * 256 + oc) * 1024 + nt * 32 + ng * 4, r);
  }
}

// ---------------------------------------------------------------------------
extern "C" void kernel_launch(void* const* d_in, const int* in_sizes, int n_in,
                              void* d_out, int out_size, void* d_ws, size_t ws_size,
                              hipStream_t stream) {
  (void)in_sizes; (void)n_in; (void)out_size; (void)ws_size;
  const float* x  = (const float*)d_in[0];
  const float* Wq = (const float*)d_in[1];
  const float* bq = (const float*)d_in[2];
  const float* Wk = (const float*)d_in[3];
  const float* bk = (const float*)d_in[4];
  const float* Wv = (const float*)d_in[5];
  const float* bv = (const float*)d_in[6];
  const float* Wo = (const float*)d_in[7];
  const float* bo = (const float*)d_in[8];
  float* out = (float*)d_out;

  char* ws = (char*)d_ws;                    // 12 MB (proven working in R15)
  u16* qw = (u16*)(ws);                      // [bh][n][d] bf16, 4MB
  u16* kw = (u16*)(ws + (4u << 20));         // [bh][n][d] bf16, 4MB
  u16* vw = (u16*)(ws + (8u << 20));         // [bh][d][n] bf16, 4MB

  r16_qkv<<<dim3(16, 8, 8), 256, 0, stream>>>(
      x, Wq, bq, Wk, bk, Wv, bv, qw, kw, vw);
  r16_attn<<<dim3(16, 64), 256, 0, stream>>>(qw, kw, vw, out);
  r16_oproj<<<dim3(32, 8), 256, 0, stream>>>(Wo, bo, out);
}

// Round 17
// 152.183 us; speedup vs baseline: 15.9375x; 1.8860x over previous
//
#include <hip/hip_runtime.h>
#include <math.h>

// Problem: B=8, C=256, N=H*W=1024, nh=8, dk=dv=32. fp32 in/out, bf16 ws.
// Round 17: all-MFMA pipeline.
//   K1 qkv : MFMA GEMM (x staged [n][c], W staged bf16/32-c chunk).
//   K2 attn: flash attention, 128-key chunks (24 barriers vs 96).
//   K3 oproj: MFMA, in-place on d_out, barrier-free K-loop.
typedef unsigned short u16;
typedef __attribute__((ext_vector_type(8))) unsigned short u16x8;
typedef __attribute__((ext_vector_type(8))) short s16x8;   // MFMA A/B frag
typedef __attribute__((ext_vector_type(4))) float f32x4;   // MFMA C/D

__device__ __forceinline__ float bf2f(u16 u) {
  union { unsigned u; float f; } c; c.u = ((unsigned)u) << 16; return c.f;
}
__device__ __forceinline__ u16 f2bf(float f) {
  union { float f; unsigned u; } c; c.f = f;
  unsigned u = c.u;
  u += 0x7fffu + ((u >> 16) & 1u);   // round-to-nearest-even
  return (u16)(u >> 16);
}
__device__ __forceinline__ u16x8 ld16(const void* p) { u16x8 v; __builtin_memcpy(&v, p, 16); return v; }
__device__ __forceinline__ void st16(void* p, u16x8 v) { __builtin_memcpy(p, &v, 16); }
__device__ __forceinline__ f32x4 ldf4(const void* p) { f32x4 v; __builtin_memcpy(&v, p, 16); return v; }
__device__ __forceinline__ void stf4(void* p, f32x4 v) { __builtin_memcpy(p, &v, 16); }
__device__ __forceinline__ s16x8 frag16(const void* p) { s16x8 v; __builtin_memcpy(&v, p, 16); return v; }
__device__ __forceinline__ s16x8 pack8(f32x4 lo, f32x4 hi) {
  u16x8 u;
  u[0] = f2bf(lo.x); u[1] = f2bf(lo.y); u[2] = f2bf(lo.z); u[3] = f2bf(lo.w);
  u[4] = f2bf(hi.x); u[5] = f2bf(hi.y); u[6] = f2bf(hi.z); u[7] = f2bf(hi.w);
  s16x8 s; __builtin_memcpy(&s, &u, 16); return s;
}

// ---------------------------------------------------------------------------
// K1: QKV projection via MFMA. Grid (16 nt, 8 h, 8 b), 256 thr (4 waves).
// Block: head h, 64-n tile. Wave w = ntile w (16 n). K=256 in 8 steps of 32.
// LDS: xt[64][264] bf16 (x^T tile, B-frag layout [n][c]) 33.8KB
//    + wlds[96][40] bf16 (Wq|Wk|Wv rows for current 32-c chunk) 7.5KB.
// Epilogue: q,k -> [bh][n][d]; v -> [bh][d][n]; scale after bias.
// ---------------------------------------------------------------------------
__global__ __launch_bounds__(256) void r17_qkv(
    const float* __restrict__ x,
    const float* __restrict__ Wq, const float* __restrict__ bq,
    const float* __restrict__ Wk, const float* __restrict__ bk,
    const float* __restrict__ Wv, const float* __restrict__ bv,
    u16* __restrict__ qo, u16* __restrict__ ko, u16* __restrict__ vo)
{
  __shared__ u16 xt[64][264];    // [n_local][c], row stride 528B (16B-mult)
  __shared__ u16 wlds[96][40];   // rows 0-31 Wq, 32-63 Wk, 64-95 Wv

  const int t = threadIdx.x;
  const int ntile = blockIdx.x, h = blockIdx.y, b = blockIdx.z;
  const int n0 = ntile * 64;
  const int w = t >> 6, lane = t & 63, l15 = lane & 15, quad = lane >> 4;

  {  // stage x^T: thread t = channel c, 64 n (fp32 -> bf16, transposed)
    const float* xrow = x + ((size_t)b * 256 + t) * 1024 + n0;
#pragma unroll
    for (int i = 0; i < 64; i += 4) {
      const f32x4 a = ldf4(xrow + i);
      xt[i + 0][t] = f2bf(a.x); xt[i + 1][t] = f2bf(a.y);
      xt[i + 2][t] = f2bf(a.z); xt[i + 3][t] = f2bf(a.w);
    }
  }

  f32x4 acc[6];
#pragma unroll
  for (int i = 0; i < 6; ++i) acc[i] = (f32x4){0.f, 0.f, 0.f, 0.f};

  for (int ks = 0; ks < 8; ++ks) {
    __syncthreads();   // protect wlds reuse (and xt staging on ks=0)
    if (t < 192) {     // stage W chunk: row = t>>1 (wave-uniform matrix)
      const int row = t >> 1, half = t & 1;
      const float* M = (row < 32) ? Wq : (row < 64) ? Wk : Wv;
      const float* src = M + (size_t)(h * 32 + (row & 31)) * 256 + ks * 32 + half * 16;
      const f32x4 a = ldf4(src),     b4 = ldf4(src + 4);
      const f32x4 c = ldf4(src + 8), d4 = ldf4(src + 12);
      u16x8 u0, u1;
#pragma unroll
      for (int i = 0; i < 4; ++i) {
        u0[i] = f2bf(a[i]);  u0[4 + i] = f2bf(b4[i]);
        u1[i] = f2bf(c[i]);  u1[4 + i] = f2bf(d4[i]);
      }
      st16(&wlds[row][half * 16], u0);
      st16(&wlds[row][half * 16 + 8], u1);
    }
    __syncthreads();

    const s16x8 bfrag = frag16(&xt[w * 16 + l15][ks * 32 + quad * 8]);
#pragma unroll
    for (int mt = 0; mt < 6; ++mt) {
      const s16x8 af = frag16(&wlds[mt * 16 + l15][quad * 8]);
      acc[mt] = __builtin_amdgcn_mfma_f32_16x16x32_bf16(af, bfrag, acc[mt], 0, 0, 0);
    }
  }

  // epilogue: C/D row = quad*4+r (d within 16), col = l15 (n within 16)
  const size_t bh = (size_t)(b * 8 + h);
  const int n = n0 + w * 16 + l15;
#pragma unroll
  for (int half = 0; half < 2; ++half) {
#pragma unroll
    for (int r = 0; r < 4; ++r) {
      const int d = half * 16 + quad * 4 + r;
      qo[(bh * 1024 + n) * 32 + d] =
          f2bf((acc[half][r] + bq[h * 32 + d]) * 0.17677669529663687f);
      ko[(bh * 1024 + n) * 32 + d] = f2bf(acc[2 + half][r] + bk[h * 32 + d]);
      vo[(bh * 32 + d) * 1024 + n] = f2bf(acc[4 + half][r] + bv[h * 32 + d]);
    }
  }
}

// ---------------------------------------------------------------------------
// K2: flash attention, mfma_f32_16x16x32_bf16, 128-key chunks (8 iters).
// Grid (16 qtiles, 64 bh); 4 waves x 16 queries. Per iter per wave:
// 8 QK MFMAs + softmax + 8 PV MFMAs, 3 barriers (24 total vs r16's 96).
// LDS overlay (35.5KB -> 4 blocks/CU): klds[128][40] | vlds[32][136] |
// plds[64][136]; otf[32][72] fp32 aliases klds after the loop.
// ---------------------------------------------------------------------------
__global__ __launch_bounds__(256) void r17_attn(
    const u16* __restrict__ qw, const u16* __restrict__ kw,
    const u16* __restrict__ vw, float* __restrict__ out)
{
  __shared__ __align__(16) char smem[36352];
  u16 (*klds)[40]  = (u16(*)[40])smem;             // [128][40]  10240B
  u16 (*vlds)[136] = (u16(*)[136])(smem + 10240);  // [32][136]   8704B
  u16 (*plds)[136] = (u16(*)[136])(smem + 18944);  // [64][136]  17408B
  float (*otf)[72] = (float(*)[72])smem;           // aliases klds post-loop

  const int t = threadIdx.x;
  const int qtile = blockIdx.x;
  const int bh = blockIdx.y;
  const int w = t >> 6, lane = t & 63, l15 = lane & 15, quad = lane >> 4;

  // A-frag: A[m=l15][k=quad*8+j] from qw[bh][n][d]
  const s16x8 qfrag = frag16(
      qw + ((size_t)bh * 1024 + qtile * 64 + w * 16 + l15) * 32 + quad * 8);

  f32x4 o0 = {0.f, 0.f, 0.f, 0.f}, o1 = {0.f, 0.f, 0.f, 0.f};
  float mrun[4], lrun[4];
#pragma unroll
  for (int r = 0; r < 4; ++r) { mrun[r] = -1e30f; lrun[r] = 0.f; }

  for (int kb = 0; kb < 8; ++kb) {
    {  // stage K[128][32] and V[32][128] (16 bf16 per thread each)
      const u16* ks_ = kw + ((size_t)bh * 1024 + kb * 128 + (t >> 1)) * 32 + (t & 1) * 16;
      st16(&klds[t >> 1][(t & 1) * 16], ld16(ks_));
      st16(&klds[t >> 1][(t & 1) * 16 + 8], ld16(ks_ + 8));
      const u16* vs_ = vw + ((size_t)bh * 32 + (t >> 3)) * 1024 + kb * 128 + (t & 7) * 16;
      st16(&vlds[t >> 3][(t & 7) * 16], ld16(vs_));
      st16(&vlds[t >> 3][(t & 7) * 16 + 8], ld16(vs_ + 8));
    }
    __syncthreads();

    // QK: 8 n-tiles of 16 keys
    f32x4 s[8];
    const f32x4 zz = {0.f, 0.f, 0.f, 0.f};
#pragma unroll
    for (int nt2 = 0; nt2 < 8; ++nt2) {
      const s16x8 kf = frag16(&klds[nt2 * 16 + l15][quad * 8]);
      s[nt2] = __builtin_amdgcn_mfma_f32_16x16x32_bf16(qfrag, kf, zz, 0, 0, 0);
    }

    // online softmax per C-row (row = quad*4+r), 128 keys
#pragma unroll
    for (int r = 0; r < 4; ++r) {
      float mx = s[0][r];
#pragma unroll
      for (int nt2 = 1; nt2 < 8; ++nt2) mx = fmaxf(mx, s[nt2][r]);
      mx = fmaxf(mx, __shfl_xor(mx, 1));
      mx = fmaxf(mx, __shfl_xor(mx, 2));
      mx = fmaxf(mx, __shfl_xor(mx, 4));
      mx = fmaxf(mx, __shfl_xor(mx, 8));
      const float mnew = fmaxf(mrun[r], mx);
      const float alpha = __expf(mrun[r] - mnew);
      float rs = 0.f;
#pragma unroll
      for (int nt2 = 0; nt2 < 8; ++nt2) {
        const float p = __expf(s[nt2][r] - mnew);
        rs += p;
        plds[w * 16 + quad * 4 + r][nt2 * 16 + l15] = f2bf(p);
      }
      rs += __shfl_xor(rs, 1);
      rs += __shfl_xor(rs, 2);
      rs += __shfl_xor(rs, 4);
      rs += __shfl_xor(rs, 8);
      lrun[r] = lrun[r] * alpha + rs;
      mrun[r] = mnew;
      o0[r] *= alpha;
      o1[r] *= alpha;
    }
    __syncthreads();   // fence plds writes -> frag reads

    // PV: K=128 in 4 steps of 32
#pragma unroll
    for (int ks = 0; ks < 4; ++ks) {
      const s16x8 pf  = frag16(&plds[w * 16 + l15][ks * 32 + quad * 8]);
      const s16x8 vf0 = frag16(&vlds[l15][ks * 32 + quad * 8]);
      const s16x8 vf1 = frag16(&vlds[16 + l15][ks * 32 + quad * 8]);
      o0 = __builtin_amdgcn_mfma_f32_16x16x32_bf16(pf, vf0, o0, 0, 0, 0);
      o1 = __builtin_amdgcn_mfma_f32_16x16x32_bf16(pf, vf1, o1, 0, 0, 0);
    }
    __syncthreads();   // protect klds/vlds/plds before next staging
  }

  // epilogue: normalize, transpose via otf (aliases klds; loop-end barrier
  // guarantees all frag reads done), coalesced fp32 stores.
#pragma unroll
  for (int r = 0; r < 4; ++r) {
    const float inv = 1.0f / lrun[r];
    otf[l15][w * 16 + quad * 4 + r]      = o0[r] * inv;
    otf[16 + l15][w * 16 + quad * 4 + r] = o1[r] * inv;
  }
  __syncthreads();
  {
    const int dd = t >> 3, i = t & 7;
    const int b = bh >> 3, hh = bh & 7;
    float* dst = out + ((size_t)b * 256 + hh * 32 + dd) * 1024 + qtile * 64 + i * 8;
    f32x4 v0, v1;
#pragma unroll
    for (int jj = 0; jj < 4; ++jj) { v0[jj] = otf[dd][i * 8 + jj];
                                     v1[jj] = otf[dd][i * 8 + 4 + jj]; }
    stf4(dst, v0); stf4(dst + 4, v1);
  }
}

// ---------------------------------------------------------------------------
// K3: out-projection via MFMA, in-place on fp32 d_out. Grid (32 nt, 8 b).
// Block owns the (b, 32-n) slab: stage slab^T [n][c] bf16 (one barrier),
// then a barrier-free K-loop: A-frags from global Wo (fp32->bf16 in regs),
// B-frags from LDS. Wave w covers oc = 64w..64w+63 (4 mtiles) x 2 ntiles.
// ---------------------------------------------------------------------------
__global__ __launch_bounds__(256) void r17_oproj(
    const float* __restrict__ Wo, const float* __restrict__ bo,
    float* __restrict__ out)
{
  __shared__ u16 o2t[32][264];   // [n_local][c], row stride 528B
  const int t = threadIdx.x;
  const int nt = blockIdx.x, b = blockIdx.y;
  const int w = t >> 6, lane = t & 63, l15 = lane & 15, quad = lane >> 4;

  {  // stage slab: thread t = channel c, 32 n (fp32 -> bf16, transposed)
    const float* src = out + ((size_t)b * 256 + t) * 1024 + nt * 32;
#pragma unroll
    for (int i = 0; i < 32; i += 4) {
      const f32x4 a = ldf4(src + i);
      o2t[i + 0][t] = f2bf(a.x); o2t[i + 1][t] = f2bf(a.y);
      o2t[i + 2][t] = f2bf(a.z); o2t[i + 3][t] = f2bf(a.w);
    }
  }
  __syncthreads();

  f32x4 acc[4][2];
#pragma unroll
  for (int mt = 0; mt < 4; ++mt) {
    acc[mt][0] = (f32x4){0.f, 0.f, 0.f, 0.f};
    acc[mt][1] = (f32x4){0.f, 0.f, 0.f, 0.f};
  }

  for (int ks = 0; ks < 8; ++ks) {
    const s16x8 b0 = frag16(&o2t[l15][ks * 32 + quad * 8]);
    const s16x8 b1 = frag16(&o2t[16 + l15][ks * 32 + quad * 8]);
#pragma unroll
    for (int mt = 0; mt < 4; ++mt) {
      const float* wsrc = Wo + (size_t)(w * 64 + mt * 16 + l15) * 256 + ks * 32 + quad * 8;
      const s16x8 af = pack8(ldf4(wsrc), ldf4(wsrc + 4));
      acc[mt][0] = __builtin_amdgcn_mfma_f32_16x16x32_bf16(af, b0, acc[mt][0], 0, 0, 0);
      acc[mt][1] = __builtin_amdgcn_mfma_f32_16x16x32_bf16(af, b1, acc[mt][1], 0, 0, 0);
    }
  }

  // epilogue: C/D row = quad*4+r (oc), col = l15 (n); coalesced per store
#pragma unroll
  for (int mt = 0; mt < 4; ++mt) {
#pragma unroll
    for (int r = 0; r < 4; ++r) {
      const int oc = w * 64 + mt * 16 + quad * 4 + r;
      const float bov = bo[oc];
      out[((size_t)b * 256 + oc) * 1024 + nt * 32 + l15]      = acc[mt][0][r] + bov;
      out[((size_t)b * 256 + oc) * 1024 + nt * 32 + 16 + l15] = acc[mt][1][r] + bov;
    }
  }
}

// ---------------------------------------------------------------------------
extern "C" void kernel_launch(void* const* d_in, const int* in_sizes, int n_in,
                              void* d_out, int out_size, void* d_ws, size_t ws_size,
                              hipStream_t stream) {
  (void)in_sizes; (void)n_in; (void)out_size; (void)ws_size;
  const float* x  = (const float*)d_in[0];
  const float* Wq = (const float*)d_in[1];
  const float* bq = (const float*)d_in[2];
  const float* Wk = (const float*)d_in[3];
  const float* bk = (const float*)d_in[4];
  const float* Wv = (const float*)d_in[5];
  const float* bv = (const float*)d_in[6];
  const float* Wo = (const float*)d_in[7];
  const float* bo = (const float*)d_in[8];
  float* out = (float*)d_out;

  char* ws = (char*)d_ws;                    // 12 MB
  u16* qw = (u16*)(ws);                      // [bh][n][d] bf16, 4MB
  u16* kw = (u16*)(ws + (4u << 20));         // [bh][n][d] bf16, 4MB
  u16* vw = (u16*)(ws + (8u << 20));         // [bh][d][n] bf16, 4MB

  r17_qkv<<<dim3(16, 8, 8), 256, 0, stream>>>(
      x, Wq, bq, Wk, bk, Wv, bv, qw, kw, vw);
  r17_attn<<<dim3(16, 64), 256, 0, stream>>>(qw, kw, vw, out);
  r17_oproj<<<dim3(32, 8), 256, 0, stream>>>(Wo, bo, out);
}